// Round 4
// baseline (904.087 us; speedup 1.0000x reference)
//
#include <hip/hip_runtime.h>

#define C_DIM 768

// d_ws layout:
//   [0)       8 x uint counts
//   [1024)    WaT4: granule (k4, o) -> float4 {Wa[o][4k4..4k4+3]}, g = k4*192 + o
//             o in [0,168): Wa rows (a*56+e*8+r); o in [168,175): w_gate col e; else 0
//   [590848)  WbT4: granule (o, c4) -> float4 {WbT[o][4c4..+3]}, g = o*192 + c4, o = a*56+k

__global__ __launch_bounds__(256) void transpose_w(
    const float* __restrict__ wa, const float* __restrict__ wg,
    const float* __restrict__ wb,
    float4* __restrict__ waT4, float4* __restrict__ wbT4) {
  const int b = blockIdx.x;
  if (b < 144) {
    const int g = b * 256 + threadIdx.x;   // 192*192 = 36864
    const int o = g % 192, k4 = g / 192;
    float4 v = make_float4(0.f, 0.f, 0.f, 0.f);
    if (o < 168) {
      v = *(const float4*)(wa + (size_t)o * C_DIM + k4 * 4);
    } else if (o < 175) {
      const int e = o - 168;
      v.x = wg[(k4 * 4 + 0) * 7 + e];
      v.y = wg[(k4 * 4 + 1) * 7 + e];
      v.z = wg[(k4 * 4 + 2) * 7 + e];
      v.w = wg[(k4 * 4 + 3) * 7 + e];
    }
    waT4[g] = v;
  } else {
    const int g = (b - 144) * 256 + threadIdx.x;   // 168*192 = 32256 exactly
    const int c4 = g % 192, ak = g / 192;
    const int a = ak / 56, k = ak - a * 56;
    const int e = k >> 3, r = k & 7;
    const float* s = wb + ((size_t)(a * 7 + e) * C_DIM + c4 * 4) * 8 + r;
    wbT4[g] = make_float4(s[0], s[8], s[16], s[24]);
  }
}

// 32 tokens/block, 4 waves x 8 tokens (round-0 proven inner structure), but
// weights are streamed through block-shared double-buffered LDS chunks
// (8 granules x 192 = 1536 float4 = 24 KB) instead of per-wave global
// register streams: global weight instrs drop ~30x (6 coalesced 1KB loads
// per thread per chunk), bytes drop 8x (per-block, not per-wave). 2-phase
// pipeline: stage c+1 -> compute c (hides load latency) -> wait -> barrier.
// LDS 81536 B/block -> exactly 2 blocks/CU; grid 512 = fully co-resident.
__global__ __launch_bounds__(256, 2) void moe_main(
    const float* __restrict__ x, const float4* __restrict__ waT4,
    const float4* __restrict__ wbT4, float* __restrict__ out,
    unsigned int* __restrict__ counts, int T) {
  __shared__ float4 wbuf[2][1536];    // 48 KB: chunk of WaT (8 k4) / WbT (8 rows)
  __shared__ float4 xbuf[2][32][8];   // 8 KB: x[t][k4-in-chunk]
  __shared__ float hsT[168][36];      // 23.6 KB: h^T [o][tok], 144B rows (16B-mult)

  const int tid = threadIdx.x;
  const int w = tid >> 6, lane = tid & 63;
  const int half = lane >> 5, l5 = lane & 31;
  const int t0 = blockIdx.x * 32;
  const int tb = w * 8;

  const int sxt = tid >> 3, sxs = tid & 7;      // x staging: token, granule
  const float4* x4 = (const float4*)x;
  const size_t xrow = (size_t)(t0 + sxt) * 192 + sxs;

  // ---- prologue: stage Wa chunk 0 + x chunk 0 into buffer 0 ----
  float4 stw[6], stx;
  #pragma unroll
  for (int j = 0; j < 6; ++j) stw[j] = waT4[tid + j * 256];
  stx = x4[xrow];
  #pragma unroll
  for (int j = 0; j < 6; ++j) wbuf[0][tid + j * 256] = stw[j];
  xbuf[0][sxt][sxs] = stx;
  __syncthreads();

  // ---------------- Stage 1: h = x @ WaT (+ gating logits) ----------------
  // half owns tokens [half*4, half*4+4); lane covers o = l5 + 32m, m=0..5
  // (rows >= 175 zero-padded). Same fp32 summation order as the 279us kernel.
  float acc1[4][6];
  #pragma unroll
  for (int tl = 0; tl < 4; ++tl)
    #pragma unroll
    for (int m = 0; m < 6; ++m) acc1[tl][m] = 0.f;

  #pragma unroll 1
  for (int c = 0; c < 24; ++c) {
    const int cb = c & 1, nb = cb ^ 1;
    // issue next chunk's global loads (latency hides under compute below)
    if (c < 23) {
      #pragma unroll
      for (int j = 0; j < 6; ++j)
        stw[j] = waT4[(size_t)(c + 1) * 1536 + tid + j * 256];
      stx = x4[xrow + (size_t)(c + 1) * 8];
    } else {
      #pragma unroll
      for (int j = 0; j < 6; ++j) stw[j] = wbT4[tid + j * 256];  // Wb chunk 0
    }
    // compute chunk c from LDS
    #pragma unroll
    for (int s = 0; s < 8; ++s) {
      float4 xv[4];
      #pragma unroll
      for (int tl = 0; tl < 4; ++tl)
        xv[tl] = xbuf[cb][tb + half * 4 + tl][s];
      #pragma unroll
      for (int m = 0; m < 6; ++m) {
        const float4 wv = wbuf[cb][s * 192 + l5 + 32 * m];
        #pragma unroll
        for (int tl = 0; tl < 4; ++tl) {
          float v = acc1[tl][m];
          v = fmaf(xv[tl].x, wv.x, v);
          v = fmaf(xv[tl].y, wv.y, v);
          v = fmaf(xv[tl].z, wv.z, v);
          v = fmaf(xv[tl].w, wv.w, v);
          acc1[tl][m] = v;
        }
      }
    }
    // hand staged regs to the other buffer, then block barrier
    #pragma unroll
    for (int j = 0; j < 6; ++j) wbuf[nb][tid + j * 256] = stw[j];
    if (c < 23) xbuf[nb][sxt][sxs] = stx;
    __syncthreads();
  }

  // ---- argmax over logits (o=168+e -> m=5, l5=8+e, same half), counts ----
  int be[4];
  #pragma unroll
  for (int tl = 0; tl < 4; ++tl) {
    float best = __shfl(acc1[tl][5], (lane & 32) + 8);
    int b = 0;
    #pragma unroll
    for (int e = 1; e < 7; ++e) {
      const float lv = __shfl(acc1[tl][5], (lane & 32) + 8 + e);
      if (lv > best) { best = lv; b = e; }   // strict > = lowest-index tie-break
    }
    be[tl] = b;
  }
  if (l5 == 0) {
    #pragma unroll
    for (int tl = 0; tl < 4; ++tl) atomicAdd(&counts[be[tl]], 1u);
  }

  // ---- scale by hierarchy coefficient, write h^T (same-wave consumer) ----
  #pragma unroll
  for (int tl = 0; tl < 4; ++tl) {
    const int b = be[tl];
    const int tcol = tb + half * 4 + tl;
    #pragma unroll
    for (int m = 0; m < 6; ++m) {
      const int o = l5 + 32 * m;
      if (o < 168) {
        const int e = (o % 56) >> 3;
        float co = (e == b) ? 1.f : 0.f;
        if (b >= 4 && e < 4) co += 0.25f;
        if (b == 6 && (e == 4 || e == 5)) co += 0.5f;
        hsT[o][tcol] = acc1[tl][m] * co;
      }
    }
  }
  // no barrier needed: each wave reads only its own hsT columns below, and
  // wbuf[0] (Wb chunk 0) was fenced by the last stage-1 __syncthreads.

  // ---------------- Stage 2: y[a] = h[a] @ WbT[a] ----------------
  float4 acc2[3][8];
  float4* out4 = (float4*)out;
  int a = 0, rc = 0;

  #pragma unroll 1
  for (int d = 0; d < 21; ++d) {   // 21 chunks of 8 WbT rows (7 per adapter)
    const int cb = d & 1, nb = cb ^ 1;
    if (d < 20) {
      #pragma unroll
      for (int j = 0; j < 6; ++j)
        stw[j] = wbT4[(size_t)(d + 1) * 1536 + tid + j * 256];
    }
    if (rc == 0) {
      #pragma unroll
      for (int cc = 0; cc < 3; ++cc)
        #pragma unroll
        for (int t = 0; t < 8; ++t) acc2[cc][t] = make_float4(0.f, 0.f, 0.f, 0.f);
    }
    const int ob = a * 56 + rc * 8;
    #pragma unroll
    for (int q = 0; q < 8; ++q) {
      const float4 hq0 = *(const float4*)&hsT[ob + q][tb];
      const float4 hq1 = *(const float4*)&hsT[ob + q][tb + 4];
      const float hv[8] = {hq0.x, hq0.y, hq0.z, hq0.w,
                           hq1.x, hq1.y, hq1.z, hq1.w};
      const float4 w0 = wbuf[cb][q * 192 + lane];
      const float4 w1 = wbuf[cb][q * 192 + lane + 64];
      const float4 w2 = wbuf[cb][q * 192 + lane + 128];
      #pragma unroll
      for (int t = 0; t < 8; ++t) {
        const float s = hv[t];
        acc2[0][t].x = fmaf(w0.x, s, acc2[0][t].x);
        acc2[0][t].y = fmaf(w0.y, s, acc2[0][t].y);
        acc2[0][t].z = fmaf(w0.z, s, acc2[0][t].z);
        acc2[0][t].w = fmaf(w0.w, s, acc2[0][t].w);
        acc2[1][t].x = fmaf(w1.x, s, acc2[1][t].x);
        acc2[1][t].y = fmaf(w1.y, s, acc2[1][t].y);
        acc2[1][t].z = fmaf(w1.z, s, acc2[1][t].z);
        acc2[1][t].w = fmaf(w1.w, s, acc2[1][t].w);
        acc2[2][t].x = fmaf(w2.x, s, acc2[2][t].x);
        acc2[2][t].y = fmaf(w2.y, s, acc2[2][t].y);
        acc2[2][t].z = fmaf(w2.z, s, acc2[2][t].z);
        acc2[2][t].w = fmaf(w2.w, s, acc2[2][t].w);
      }
    }
    if (rc == 6) {   // finished adapter a: write y
      #pragma unroll
      for (int cc = 0; cc < 3; ++cc)
        #pragma unroll
        for (int t = 0; t < 8; ++t)
          out4[((size_t)a * T + t0 + tb + t) * 192 + cc * 64 + lane] = acc2[cc][t];
      ++a; rc = 0;
    } else {
      ++rc;
    }
    if (d < 20) {
      #pragma unroll
      for (int j = 0; j < 6; ++j) wbuf[nb][tid + j * 256] = stw[j];
      __syncthreads();
    }
  }
}

// loss = 2 * cv2(counts)  (importance == load == counts when K=1, gate==1.0)
__global__ void loss_k(const unsigned int* __restrict__ counts,
                       float* __restrict__ out, int T) {
  if (threadIdx.x == 0) {
    float c[7], mean = 0.f;
    #pragma unroll
    for (int e = 0; e < 7; ++e) { c[e] = (float)counts[e]; mean += c[e]; }
    mean *= (1.f / 7.f);
    float var = 0.f;
    #pragma unroll
    for (int e = 0; e < 7; ++e) { const float d = c[e] - mean; var += d * d; }
    var *= (1.f / 6.f);  // ddof=1
    out[(size_t)3 * T * C_DIM] = 2.f * (var / (mean * mean + 1e-10f));
  }
}

extern "C" void kernel_launch(void* const* d_in, const int* in_sizes, int n_in,
                              void* d_out, int out_size, void* d_ws, size_t ws_size,
                              hipStream_t stream) {
  const float* x  = (const float*)d_in[0];
  const float* wg = (const float*)d_in[1];
  const float* Wa = (const float*)d_in[2];
  const float* Wb = (const float*)d_in[3];
  float* out = (float*)d_out;

  unsigned int* counts = (unsigned int*)d_ws;
  float4* waT4 = (float4*)((char*)d_ws + 1024);
  float4* wbT4 = (float4*)((char*)d_ws + 590848);

  const int T = in_sizes[0] / C_DIM;  // 16384

  hipMemsetAsync(counts, 0, 8 * sizeof(unsigned int), stream);
  transpose_w<<<dim3(270), dim3(256), 0, stream>>>(Wa, wg, Wb, waT4, wbT4);
  moe_main<<<dim3(T / 32), dim3(256), 0, stream>>>(x, waT4, wbT4, out, counts, T);
  loss_k<<<dim3(1), dim3(64), 0, stream>>>(counts, out, T);
}

// Round 5
// 599.538 us; speedup vs baseline: 1.5080x; 1.5080x over previous
//
#include <hip/hip_runtime.h>

#define C_DIM 768

// d_ws layout:
//   [0)       8 x uint counts
//   [1024)    WaT4: granule (k4, o) -> float4 {Wa[o][4k4..4k4+3]}, g = k4*192 + o
//             o in [0,168): Wa rows (a*56+e*8+r); o in [168,175): w_gate col e; else 0
//   [590848)  WbT4: granule (o, c4) -> float4 {WbT[o][4c4..+3]}, g = o*192 + c4, o = a*56+k

__global__ __launch_bounds__(256) void transpose_w(
    const float* __restrict__ wa, const float* __restrict__ wg,
    const float* __restrict__ wb,
    float4* __restrict__ waT4, float4* __restrict__ wbT4) {
  const int b = blockIdx.x;
  if (b < 144) {
    const int g = b * 256 + threadIdx.x;   // 192*192 = 36864
    const int o = g % 192, k4 = g / 192;
    float4 v = make_float4(0.f, 0.f, 0.f, 0.f);
    if (o < 168) {
      v = *(const float4*)(wa + (size_t)o * C_DIM + k4 * 4);
    } else if (o < 175) {
      const int e = o - 168;
      v.x = wg[(k4 * 4 + 0) * 7 + e];
      v.y = wg[(k4 * 4 + 1) * 7 + e];
      v.z = wg[(k4 * 4 + 2) * 7 + e];
      v.w = wg[(k4 * 4 + 3) * 7 + e];
    }
    waT4[g] = v;
  } else {
    const int g = (b - 144) * 256 + threadIdx.x;   // 168*192 = 32256 exactly
    const int c4 = g % 192, ak = g / 192;
    const int a = ak / 56, k = ak - a * 56;
    const int e = k >> 3, r = k & 7;
    const float* s = wb + ((size_t)(a * 7 + e) * C_DIM + c4 * 4) * 8 + r;
    wbT4[g] = make_float4(s[0], s[8], s[16], s[24]);
  }
}

// 16 tokens/block, 4 waves; weights stream through block-shared double-buffered
// LDS chunks of 4 granules/rows (768 float4 = 12 KB each). Register-bucket
// discipline (round-4 lesson: live>128 => allocator pins 128 and spills 2GB):
// stage-2 live ~95 (acc2[3][4]=48 + stw 12 + w 12 + misc), stage-1 ~65 -> clean
// <=128 alloc -> 4 waves/SIMD. LDS 40.1 KB -> 4 blocks/CU; grid 1024 = fully
// co-resident (256 CU x 4). Stage-1 uses 64-lane o-split (o = lane + 64m):
// 12 weight ds_reads + broadcast x reads per chunk (half the LDS-pipe load of
// the 32-lane split).
__global__ __launch_bounds__(256, 2) void moe_main(
    const float* __restrict__ x, const float4* __restrict__ waT4,
    const float4* __restrict__ wbT4, float* __restrict__ out,
    unsigned int* __restrict__ counts, int T) {
  __shared__ float4 wbuf[2][768];     // 24 KB: WaT chunk (4 k4) / WbT chunk (4 rows)
  __shared__ float4 xbuf[2][16][4];   // 2 KB: x[t][granule-in-chunk]
  __shared__ float hsT[168][20];      // 13.1 KB: h^T [o][tok], 80B rows (16B-mult)

  const int tid = threadIdx.x;
  const int w = tid >> 6, lane = tid & 63;
  const int t0 = blockIdx.x * 16;
  const int tb = w * 4;

  const float4* x4 = (const float4*)x;
  // x staging: lanes<16 of each wave load its own 4 tokens x 4 granules
  const int sxt = tb + (lane >> 2), sxs = lane & 3;
  const size_t xrow = (size_t)(t0 + sxt) * 192 + sxs;

  // ---- prologue: stage Wa chunk 0 + x chunk 0 into buffer 0 ----
  float4 stw[3], stx;
  #pragma unroll
  for (int j = 0; j < 3; ++j) stw[j] = waT4[tid + j * 256];
  if (lane < 16) stx = x4[xrow];
  #pragma unroll
  for (int j = 0; j < 3; ++j) wbuf[0][tid + j * 256] = stw[j];
  if (lane < 16) xbuf[0][sxt][sxs] = stx;
  __syncthreads();

  // ---------------- Stage 1: h = x @ WaT (+ gating logits) ----------------
  // lane covers o = lane + 64m, m=0..2 (rows >=175 zero-padded); all 4 of the
  // wave's tokens accumulate per lane. k-order ascending (bit-stable fp32 sum).
  float acc1[4][3];
  #pragma unroll
  for (int tl = 0; tl < 4; ++tl)
    #pragma unroll
    for (int m = 0; m < 3; ++m) acc1[tl][m] = 0.f;

  #pragma unroll 1
  for (int c = 0; c < 48; ++c) {
    const int cb = c & 1, nb = cb ^ 1;
    // issue next chunk's global loads (latency hides under the 192 FMAs below)
    if (c < 47) {
      #pragma unroll
      for (int j = 0; j < 3; ++j)
        stw[j] = waT4[(size_t)(c + 1) * 768 + tid + j * 256];
      if (lane < 16) stx = x4[xrow + (size_t)(c + 1) * 4];
    } else {
      #pragma unroll
      for (int j = 0; j < 3; ++j) stw[j] = wbT4[tid + j * 256];  // Wb chunk 0
    }
    // compute chunk c from LDS
    #pragma unroll
    for (int s = 0; s < 4; ++s) {
      float4 xv[4];
      #pragma unroll
      for (int tl = 0; tl < 4; ++tl) xv[tl] = xbuf[cb][tb + tl][s];  // broadcast
      #pragma unroll
      for (int m = 0; m < 3; ++m) {
        const float4 wv = wbuf[cb][s * 192 + lane + 64 * m];  // contiguous
        #pragma unroll
        for (int tl = 0; tl < 4; ++tl) {
          float v = acc1[tl][m];
          v = fmaf(xv[tl].x, wv.x, v);
          v = fmaf(xv[tl].y, wv.y, v);
          v = fmaf(xv[tl].z, wv.z, v);
          v = fmaf(xv[tl].w, wv.w, v);
          acc1[tl][m] = v;
        }
      }
    }
    // hand staged regs to the other buffer, block barrier
    #pragma unroll
    for (int j = 0; j < 3; ++j) wbuf[nb][tid + j * 256] = stw[j];
    if (c < 47 && lane < 16) xbuf[nb][sxt][sxs] = stx;
    __syncthreads();
  }

  // ---- argmax over logits (o = 168+e -> m=2, lane = 40+e), counts ----
  int be[4];
  #pragma unroll
  for (int tl = 0; tl < 4; ++tl) {
    float best = __shfl(acc1[tl][2], 40);
    int b = 0;
    #pragma unroll
    for (int e = 1; e < 7; ++e) {
      const float lv = __shfl(acc1[tl][2], 40 + e);
      if (lv > best) { best = lv; b = e; }   // strict > = lowest-index tie-break
    }
    be[tl] = b;
  }
  if (lane == 0) {
    #pragma unroll
    for (int tl = 0; tl < 4; ++tl) atomicAdd(&counts[be[tl]], 1u);
  }

  // ---- scale by hierarchy coefficient, write h^T (same-wave consumer) ----
  #pragma unroll
  for (int tl = 0; tl < 4; ++tl) {
    const int b = be[tl];
    #pragma unroll
    for (int m = 0; m < 3; ++m) {
      const int o = lane + 64 * m;
      if (o < 168) {
        const int e = (o % 56) >> 3;
        float co = (e == b) ? 1.f : 0.f;
        if (b >= 4 && e < 4) co += 0.25f;
        if (b == 6 && (e == 4 || e == 5)) co += 0.5f;
        hsT[o][tb + tl] = acc1[tl][m] * co;
      }
    }
  }
  // no extra barrier: each wave wrote and reads only its own hsT columns, and
  // wbuf[0] (Wb chunk 0) was fenced by the last stage-1 __syncthreads.

  // ---------------- Stage 2: y[a] = h[a] @ WbT[a] ----------------
  // 42 chunks of 4 WbT rows (14 per adapter; 56%4==0 so no straddling).
  float4 acc2[3][4];
  float4* out4 = (float4*)out;

  #pragma unroll 1
  for (int a = 0; a < 3; ++a) {
    #pragma unroll
    for (int cc = 0; cc < 3; ++cc)
      #pragma unroll
      for (int t = 0; t < 4; ++t) acc2[cc][t] = make_float4(0.f, 0.f, 0.f, 0.f);

    #pragma unroll 1
    for (int dd = 0; dd < 14; ++dd) {
      const int d = a * 14 + dd;
      const int cb = d & 1, nb = cb ^ 1;
      if (d < 41) {
        #pragma unroll
        for (int j = 0; j < 3; ++j)
          stw[j] = wbT4[(size_t)(d + 1) * 768 + tid + j * 256];
      }
      #pragma unroll
      for (int q = 0; q < 4; ++q) {
        const int o = d * 4 + q;                         // global row a*56+k
        const float4 hq = *(const float4*)&hsT[o][tb];   // wave-uniform
        const float hv[4] = {hq.x, hq.y, hq.z, hq.w};
        const float4 w0 = wbuf[cb][q * 192 + lane];
        const float4 w1 = wbuf[cb][q * 192 + 64 + lane];
        const float4 w2 = wbuf[cb][q * 192 + 128 + lane];
        #pragma unroll
        for (int t = 0; t < 4; ++t) {
          const float s = hv[t];
          acc2[0][t].x = fmaf(w0.x, s, acc2[0][t].x);
          acc2[0][t].y = fmaf(w0.y, s, acc2[0][t].y);
          acc2[0][t].z = fmaf(w0.z, s, acc2[0][t].z);
          acc2[0][t].w = fmaf(w0.w, s, acc2[0][t].w);
          acc2[1][t].x = fmaf(w1.x, s, acc2[1][t].x);
          acc2[1][t].y = fmaf(w1.y, s, acc2[1][t].y);
          acc2[1][t].z = fmaf(w1.z, s, acc2[1][t].z);
          acc2[1][t].w = fmaf(w1.w, s, acc2[1][t].w);
          acc2[2][t].x = fmaf(w2.x, s, acc2[2][t].x);
          acc2[2][t].y = fmaf(w2.y, s, acc2[2][t].y);
          acc2[2][t].z = fmaf(w2.z, s, acc2[2][t].z);
          acc2[2][t].w = fmaf(w2.w, s, acc2[2][t].w);
        }
      }
      if (d < 41) {
        #pragma unroll
        for (int j = 0; j < 3; ++j) wbuf[nb][tid + j * 256] = stw[j];
        __syncthreads();
      }
    }

    // write adapter a (coalesced 1KB/wave stores; overlaps next a's LDS work)
    #pragma unroll
    for (int cc = 0; cc < 3; ++cc)
      #pragma unroll
      for (int t = 0; t < 4; ++t)
        out4[((size_t)a * T + t0 + tb + t) * 192 + cc * 64 + lane] = acc2[cc][t];
  }
}

// loss = 2 * cv2(counts)  (importance == load == counts when K=1, gate==1.0)
__global__ void loss_k(const unsigned int* __restrict__ counts,
                       float* __restrict__ out, int T) {
  if (threadIdx.x == 0) {
    float c[7], mean = 0.f;
    #pragma unroll
    for (int e = 0; e < 7; ++e) { c[e] = (float)counts[e]; mean += c[e]; }
    mean *= (1.f / 7.f);
    float var = 0.f;
    #pragma unroll
    for (int e = 0; e < 7; ++e) { const float d = c[e] - mean; var += d * d; }
    var *= (1.f / 6.f);  // ddof=1
    out[(size_t)3 * T * C_DIM] = 2.f * (var / (mean * mean + 1e-10f));
  }
}

extern "C" void kernel_launch(void* const* d_in, const int* in_sizes, int n_in,
                              void* d_out, int out_size, void* d_ws, size_t ws_size,
                              hipStream_t stream) {
  const float* x  = (const float*)d_in[0];
  const float* wg = (const float*)d_in[1];
  const float* Wa = (const float*)d_in[2];
  const float* Wb = (const float*)d_in[3];
  float* out = (float*)d_out;

  unsigned int* counts = (unsigned int*)d_ws;
  float4* waT4 = (float4*)((char*)d_ws + 1024);
  float4* wbT4 = (float4*)((char*)d_ws + 590848);

  const int T = in_sizes[0] / C_DIM;  // 16384

  hipMemsetAsync(counts, 0, 8 * sizeof(unsigned int), stream);
  transpose_w<<<dim3(270), dim3(256), 0, stream>>>(Wa, wg, Wb, waT4, wbT4);
  moe_main<<<dim3(T / 16), dim3(256), 0, stream>>>(x, waT4, wbT4, out, counts, T);
  loss_k<<<dim3(1), dim3(64), 0, stream>>>(counts, out, T);
}

// Round 7
// 393.295 us; speedup vs baseline: 2.2988x; 1.5244x over previous
//
#include <hip/hip_runtime.h>

#define C_DIM 768

// d_ws layout:
//   [0)        8 x uint counts
//   [1024)     WaT4: granule (k4, o) -> float4 {Wa[o][4k4..+3]}, g = k4*192 + o
//              o in [0,168): Wa rows (a*56+e*8+r); o in [168,175): w_gate col e; else 0
//   [590848)   WbT4: granule (o, c4) -> float4 {WbT[o][4c4..+3]}, g = o*192 + c4, o = a*56+k
//   [1110016)  hT: float [168][T] -- scaled h^T, written by stage1, read by stage2

__global__ __launch_bounds__(256) void transpose_w(
    const float* __restrict__ wa, const float* __restrict__ wg,
    const float* __restrict__ wb,
    float4* __restrict__ waT4, float4* __restrict__ wbT4) {
  const int b = blockIdx.x;
  if (b < 144) {
    const int g = b * 256 + threadIdx.x;   // 192*192 = 36864
    const int o = g % 192, k4 = g / 192;
    float4 v = make_float4(0.f, 0.f, 0.f, 0.f);
    if (o < 168) {
      v = *(const float4*)(wa + (size_t)o * C_DIM + k4 * 4);
    } else if (o < 175) {
      const int e = o - 168;
      v.x = wg[(k4 * 4 + 0) * 7 + e];
      v.y = wg[(k4 * 4 + 1) * 7 + e];
      v.z = wg[(k4 * 4 + 2) * 7 + e];
      v.w = wg[(k4 * 4 + 3) * 7 + e];
    }
    waT4[g] = v;
  } else {
    const int g = (b - 144) * 256 + threadIdx.x;   // 168*192 = 32256 exactly
    const int c4 = g % 192, ak = g / 192;
    const int a = ak / 56, k = ak - a * 56;
    const int e = k >> 3, r = k & 7;
    const float* s = wb + ((size_t)(a * 7 + e) * C_DIM + c4 * 4) * 8 + r;
    wbT4[g] = make_float4(s[0], s[8], s[16], s[24]);
  }
}

// ---------------- Stage 1 kernel: h^T = scale(x @ WaT), routing ----------------
// 8 tokens/block, 4 waves, wave = k-quarter (48 of 192 k4-granules).
// acc[8][3]=24 + wv 24 -> live ~60 VGPR: below every allocator tier (rounds
// 1/4/5 lesson: live > tier => spill traffic). 2048 blocks x 4 = 8192 waves
// (~5-8/SIMD resident). Per-wave x staged to LDS (no cross-wave deps);
// k-partials reduced via LDS float atomics (R2-proven numerics).
__global__ __launch_bounds__(256, 2) void stage1(
    const float* __restrict__ x, const float4* __restrict__ waT4,
    float* __restrict__ hT, unsigned int* __restrict__ counts, int T) {
  __shared__ float4 xw[4][384];   // 24 KB: per-wave x[8 tok][48 gran]
  __shared__ float hs[192 * 9];   // 6.9 KB: h partial sums, stride 9 (bank-spread)
  __shared__ int bes[8];

  const int tid = threadIdx.x;
  const int w = tid >> 6, lane = tid & 63;
  const int t0 = blockIdx.x * 8;

  for (int g = tid; g < 192 * 9; g += 256) hs[g] = 0.f;

  const float4* x4 = (const float4*)x;
  #pragma unroll
  for (int j = 0; j < 6; ++j) {
    const int f = lane + 64 * j;           // 0..383
    const int t = f / 48, s = f - t * 48;
    xw[w][f] = x4[(size_t)(t0 + t) * 192 + w * 48 + s];
  }
  __syncthreads();

  float acc[8][3];
  #pragma unroll
  for (int t = 0; t < 8; ++t)
    #pragma unroll
    for (int m = 0; m < 3; ++m) acc[t][m] = 0.f;

  // lane covers o = lane + 64m (rows >=175 zero-padded); k ascending per wave.
  const float4* wa_p = waT4 + (size_t)(w * 48) * 192 + lane;
  float4 wv[2][3];
  #pragma unroll
  for (int m = 0; m < 3; ++m) wv[0][m] = wa_p[64 * m];
  #pragma unroll
  for (int m = 0; m < 3; ++m) wv[1][m] = wa_p[192 + 64 * m];

  #pragma unroll 2
  for (int s = 0; s < 48; ++s) {
    const int p = s & 1;
    #pragma unroll
    for (int t = 0; t < 8; ++t) {
      const float4 xv = xw[w][t * 48 + s];   // wave-uniform broadcast
      #pragma unroll
      for (int m = 0; m < 3; ++m) {
        float v = acc[t][m];
        v = fmaf(xv.x, wv[p][m].x, v);
        v = fmaf(xv.y, wv[p][m].y, v);
        v = fmaf(xv.z, wv[p][m].z, v);
        v = fmaf(xv.w, wv[p][m].w, v);
        acc[t][m] = v;
      }
    }
    int sn = s + 2; sn = sn > 47 ? 47 : sn;  // prefetch s+2 (clamped tail)
    #pragma unroll
    for (int m = 0; m < 3; ++m) wv[p][m] = wa_p[(size_t)sn * 192 + 64 * m];
  }

  // k-quarter reduction: LDS float atomics. Banks: (o*9+t)%32, 9 coprime 32
  // -> lanes 0..31 distinct banks, lane l vs l+32 2-way (free).
  #pragma unroll
  for (int m = 0; m < 3; ++m) {
    const int o = lane + 64 * m;
    #pragma unroll
    for (int t = 0; t < 8; ++t) atomicAdd(&hs[o * 9 + t], acc[t][m]);
  }
  __syncthreads();

  // argmax over logits rows 168..174 (thread = token), strict > tie-break
  if (tid < 8) {
    const int t = tid;
    float best = hs[168 * 9 + t];
    int b = 0;
    #pragma unroll
    for (int e = 1; e < 7; ++e) {
      const float lv = hs[(168 + e) * 9 + t];
      if (lv > best) { best = lv; b = e; }
    }
    bes[t] = b;
    atomicAdd(&counts[b], 1u);
  }
  __syncthreads();

  // scale by hierarchy coefficient, store h^T[o][t0+t]
  for (int g = tid; g < 168 * 8; g += 256) {
    const int o = g >> 3, t = g & 7;
    const int e = (o % 56) >> 3, b = bes[t];
    float co = (e == b) ? 1.f : 0.f;
    if (b >= 4 && e < 4) co += 0.25f;
    if (b == 6 && (e == 4 || e == 5)) co += 0.5f;
    hT[(size_t)o * T + t0 + t] = hs[o * 9 + t] * co;
  }
}

// ---------------- Stage 2 kernel: y[a] = h[a] @ WbT[a] ----------------
// grid (T/32, 3): block = (32 tokens, one adapter) -> 1536 blocks x 4 waves
// = 6144 waves (~6/SIMD). Wave = 8 tokens; 3 sequential c-third passes with
// acc[8] float4 = 32 regs (live ~60, spill-proof). Weight granules read once
// per wave total (each pass reads a distinct c-column). h tile staged once
// (7 KB, one barrier -- strided over the 256 threads: ROUND-6 BUG was
// `if (tid < 448)` with a 256-thread block, leaving hl[32..55] unwritten);
// zero barriers in the main loop.
__global__ __launch_bounds__(256, 2) void stage2(
    const float* __restrict__ hT, const float4* __restrict__ wbT4,
    float* __restrict__ out, int T) {
  __shared__ float hl[56][32];   // 7 KB

  const int tid = threadIdx.x;
  const int w = tid >> 6, lane = tid & 63;
  const int a = blockIdx.y;
  const int t0 = blockIdx.x * 32;
  const int tb = w * 8;

  for (int idx = tid; idx < 448; idx += 256) {   // 56 rows x 8 float4-cols
    const int k = idx >> 3, t4 = idx & 7;
    *(float4*)&hl[k][t4 * 4] =
        *(const float4*)&hT[(size_t)(a * 56 + k) * T + t0 + t4 * 4];
  }
  __syncthreads();

  const float4* wb_l = wbT4 + (size_t)(a * 56) * 192 + lane;
  float4* out4 = (float4*)out;

  #pragma unroll 1
  for (int cc = 0; cc < 3; ++cc) {
    const float4* wp = wb_l + cc * 64;
    float4 acc[8];
    #pragma unroll
    for (int t = 0; t < 8; ++t) acc[t] = make_float4(0.f, 0.f, 0.f, 0.f);

    float4 u0 = wp[0];
    float4 u1 = wp[192];

    #pragma unroll 4
    for (int k = 0; k < 56; ++k) {
      const float4 u = (k & 1) ? u1 : u0;
      int kn = k + 2; kn = kn > 55 ? 55 : kn;   // prefetch k+2 (clamped tail)
      const float4 un = wp[(size_t)kn * 192];
      const float4 h0 = *(const float4*)&hl[k][tb];       // wave-uniform
      const float4 h1 = *(const float4*)&hl[k][tb + 4];
      const float hv[8] = {h0.x, h0.y, h0.z, h0.w, h1.x, h1.y, h1.z, h1.w};
      #pragma unroll
      for (int t = 0; t < 8; ++t) {
        const float s = hv[t];
        acc[t].x = fmaf(u.x, s, acc[t].x);
        acc[t].y = fmaf(u.y, s, acc[t].y);
        acc[t].z = fmaf(u.z, s, acc[t].z);
        acc[t].w = fmaf(u.w, s, acc[t].w);
      }
      if (k & 1) u1 = un; else u0 = un;
    }

    #pragma unroll
    for (int t = 0; t < 8; ++t)
      out4[((size_t)a * T + t0 + tb + t) * 192 + cc * 64 + lane] = acc[t];
  }
}

// loss = 2 * cv2(counts)  (importance == load == counts when K=1, gate==1.0)
__global__ void loss_k(const unsigned int* __restrict__ counts,
                       float* __restrict__ out, int T) {
  if (threadIdx.x == 0) {
    float c[7], mean = 0.f;
    #pragma unroll
    for (int e = 0; e < 7; ++e) { c[e] = (float)counts[e]; mean += c[e]; }
    mean *= (1.f / 7.f);
    float var = 0.f;
    #pragma unroll
    for (int e = 0; e < 7; ++e) { const float d = c[e] - mean; var += d * d; }
    var *= (1.f / 6.f);  // ddof=1
    out[(size_t)3 * T * C_DIM] = 2.f * (var / (mean * mean + 1e-10f));
  }
}

extern "C" void kernel_launch(void* const* d_in, const int* in_sizes, int n_in,
                              void* d_out, int out_size, void* d_ws, size_t ws_size,
                              hipStream_t stream) {
  const float* x  = (const float*)d_in[0];
  const float* wg = (const float*)d_in[1];
  const float* Wa = (const float*)d_in[2];
  const float* Wb = (const float*)d_in[3];
  float* out = (float*)d_out;

  unsigned int* counts = (unsigned int*)d_ws;
  float4* waT4 = (float4*)((char*)d_ws + 1024);
  float4* wbT4 = (float4*)((char*)d_ws + 590848);
  float* hT    = (float*)((char*)d_ws + 1110016);

  const int T = in_sizes[0] / C_DIM;  // 16384

  hipMemsetAsync(counts, 0, 8 * sizeof(unsigned int), stream);
  transpose_w<<<dim3(270), dim3(256), 0, stream>>>(Wa, wg, Wb, waT4, wbT4);
  stage1<<<dim3(T / 8), dim3(256), 0, stream>>>(x, waT4, hT, counts, T);
  stage2<<<dim3(T / 32, 3), dim3(256), 0, stream>>>(hT, wbT4, out, T);
  loss_k<<<dim3(1), dim3(64), 0, stream>>>(counts, out, T);
}